// Round 8
// baseline (439.173 us; speedup 1.0000x reference)
//
#include <hip/hip_runtime.h>
#include <math.h>

typedef __bf16 bf16;
typedef __bf16 bf16x8 __attribute__((ext_vector_type(8)));
typedef __bf16 bf16x4 __attribute__((ext_vector_type(4)));
typedef float  f32x4  __attribute__((ext_vector_type(4)));

#define HW        16384      // 128*128
#define OUT_ELEMS 4194304    // 4*64*128*128

// xm: [b][m][row 142][CHUNK-MAJOR row: ch8][px142][c8]; pixel (y,x) at row y+7, px x+7
#define XM_ROW    9088                    // 142*64 el per row
#define XM_PLANE  (142 * XM_ROW)          // 1,290,496 el
// cat: [b][row130][di4][CHUNK-MAJOR slice: ch8][px130][c8]; pixel (y,x) at row y+1, px x+1
#define CAT_DI    8320                    // 130*64 el
#define CAT_ROW   (4 * CAT_DI)            // 33,280
#define CAT_PLANE (130 * CAT_ROW)         // 4,326,400 el

// LDS buffers (elements): 1280 16B-chunks = 10240 el = 20,480 B per buffer
#define LBUF 10240

typedef const __attribute__((address_space(1))) void* gas1;
typedef __attribute__((address_space(3))) void* las3;

// ---------------- weight transforms (fp32 -> bf16, tap-major, c innermost) ----
__global__ void k_wt(const float* __restrict__ kern, const float* __restrict__ w2,
                     bf16* __restrict__ kern_t, bf16* __restrict__ w2_t) {
  int i = blockIdx.x * 256 + threadIdx.x;
  const int N1 = 4 * 3 * 9 * 64 * 64;   // 442368
  if (i < N1) {
    int c = i & 63, o = (i >> 6) & 63, tap = (i >> 12) % 9, bm = i / 36864;
    kern_t[i] = (bf16)kern[(((bm * 64 + o) * 64 + c) * 9) + tap];
  } else {
    int j = i - N1;
    if (j < 64 * 256 * 9) {
      int ch = j & 255, oc = (j >> 8) & 63, tap = j >> 14;
      w2_t[j] = (bf16)w2[(oc * 256 + ch) * 9 + tap];
    }
  }
}

// -------- mask conv stage 1: partial logits over 8-channel groups ------------
__global__ void k_mask1(const float* __restrict__ x, const float* __restrict__ mw,
                        float* __restrict__ part) {
  int y = blockIdx.x, b = blockIdx.y, cg = blockIdx.z;
  int tx = threadIdx.x;      // 0..127
  float a0 = 0.f, a1 = 0.f, a2 = 0.f;
#pragma unroll
  for (int ci = 0; ci < 8; ++ci) {
    int c = cg * 8 + ci;
    const float* xp = x + ((size_t)(b * 64 + c)) * HW;
    const float* w0 = mw + (0 * 64 + c) * 9;
    const float* w1 = mw + (1 * 64 + c) * 9;
    const float* w2 = mw + (2 * 64 + c) * 9;
#pragma unroll
    for (int ky = 0; ky < 3; ++ky) {
      int yy = y + ky - 1;
      if ((unsigned)yy >= 128u) continue;
#pragma unroll
      for (int kx = 0; kx < 3; ++kx) {
        int xx = tx + kx - 1;
        if ((unsigned)xx >= 128u) continue;
        float xv = xp[yy * 128 + xx];
        a0 += xv * w0[ky * 3 + kx];
        a1 += xv * w1[ky * 3 + kx];
        a2 += xv * w2[ky * 3 + kx];
      }
    }
  }
  size_t base = (size_t)((b * 8 + cg) * 3) * HW + y * 128 + tx;
  part[base]          = a0;
  part[base + HW]     = a1;
  part[base + 2 * HW] = a2;
}

// -------- mask conv stage 2: reduce groups + bias + softmax ------------------
__global__ void k_mask2(const float* __restrict__ part, const float* __restrict__ mb,
                        float* __restrict__ masks) {
  int y = blockIdx.x, b = blockIdx.y;
  int tx = threadIdx.x;
  float a0 = mb[0], a1 = mb[1], a2 = mb[2];
  int off = y * 128 + tx;
#pragma unroll
  for (int cg = 0; cg < 8; ++cg) {
    size_t base = (size_t)((b * 8 + cg) * 3) * HW + off;
    a0 += part[base];
    a1 += part[base + HW];
    a2 += part[base + 2 * HW];
  }
  float mx = fmaxf(a0, fmaxf(a1, a2));
  float e0 = __expf(a0 - mx), e1 = __expf(a1 - mx), e2 = __expf(a2 - mx);
  float inv = 1.0f / (e0 + e1 + e2);
  size_t base = ((size_t)b * 3) * HW + off;
  masks[base]          = e0 * inv;
  masks[base + HW]     = e1 * inv;
  masks[base + 2 * HW] = e2 * inv;
}

// -------- xm = x * mask -> chunk-major padded rows, incl. halo zeroing -------
__global__ void k_xmt(const float* __restrict__ x, const float* __restrict__ masks,
                      bf16* __restrict__ xm_p) {
  int yp = blockIdx.x;  // 0..141 padded row
  int m = blockIdx.y, b = blockIdx.z;
  int t = threadIdx.x;  // 256
  bf16* prow = xm_p + (size_t)(b * 3 + m) * XM_PLANE + (size_t)yp * XM_ROW;
  bf16x8 z = {};
  if (yp < 7 || yp >= 135) {          // full halo row: 1136 16B-chunks
#pragma unroll
    for (int i = 0; i < 5; ++i) {
      int u = i * 256 + t;
      if (u < 1136) *(bf16x8*)(prow + u * 8) = z;
    }
    return;
  }
  // side halos: per chunk, px 0..6 (el 0..55) and px 135..141 (el 1080..1135)
  if (t < 112) {
    int ch = t / 14, rem = t % 14, side = rem / 7, j = rem % 7;
    *(bf16x8*)(prow + ch * 1136 + side * 1080 + j * 8) = z;
  }

  int y = yp - 7;
  __shared__ float tile[64 * 130];
#pragma unroll
  for (int i = 0; i < 32; ++i) {
    int u = i * 256 + t;           // 0..8191
    int c = u >> 7, xx = u & 127;
    tile[c * 130 + xx] = x[((size_t)(b * 64 + c)) * HW + y * 128 + xx];
  }
  __syncthreads();
  const float* mrow = masks + ((size_t)(b * 3 + m)) * HW + y * 128;
#pragma unroll
  for (int i = 0; i < 32; ++i) {
    int u = i * 256 + t;
    int c = u & 63, xx = u >> 6;
    prow[(c >> 3) * 1136 + (xx + 7) * 8 + (c & 7)] = (bf16)(tile[c * 130 + xx] * mrow[xx]);
  }
}

// ---------------- zero the halo of cat_p (chunk-major slices) ----------------
__global__ void k_cat_halo(bf16* __restrict__ cat_p) {
  int id = blockIdx.x * 256 + threadIdx.x;
  if (id >= 4 * 16512) return;
  int plane = id / 16512, j = id % 16512;
  bf16* base = cat_p + (size_t)plane * CAT_PLANE;
  bf16x8 zv = {};
  if (j < 8320) {                         // rows 0 and 129 full: 4160 chunks each
    int row = (j / 4160) * 129;
    int off = (j % 4160) * 8;
    *(bf16x8*)(base + (size_t)row * CAT_ROW + off) = zv;
  } else {                                // rows 1..128: px 0 and 129 per (di,ch)
    int k = j - 8320;                     // 0..8191 = 128 rows * 64
    int row = 1 + (k >> 6);
    int idx = k & 63;                     // di(2b) ch(3b) side(1b)
    int di = idx >> 4, ch = (idx >> 1) & 7, side = idx & 1;
    *(bf16x8*)(base + (size_t)row * CAT_ROW + di * CAT_DI + ch * 1040 + side * 129 * 8) = zv;
  }
}

// ------- branch convs: global_load_lds dbuf pipeline, 1 row/block ------------
// block = 256 thr (4 waves), tile = 64 o x 128 px x 1 row. 9 phases (m,ky):
// DMA next phase's xm row into LDS buf[nxt] right AFTER the barrier -> full
// compute phase in flight; barrier's vmcnt(0) drain is then nearly free.
__global__ __launch_bounds__(256, 3) void k_branch(const bf16* __restrict__ xm_p,
                                                   const bf16* __restrict__ kern_t,
                                                   bf16* __restrict__ cat_p) {
  __shared__ bf16 sb[2 * LBUF];   // 40,960 B
  int bid = blockIdx.x;
  int xcd = bid & 7;
  int i   = bid >> 3;          // 0..255
  int b   = xcd >> 1;
  int di  = ((xcd & 1) << 1) | (i & 1);
  int y   = i >> 1;            // 0..127
  int d   = 1 + 2 * di;
  int t    = threadIdx.x;
  int lane = t & 63;
  int w    = t >> 6;           // wave 0..3: px quarter
  int lanelo = lane & 15;
  int quad = lane >> 4;

  const bf16* plane0 = xm_p + (size_t)(b * 3) * XM_PLANE;
  const bf16* wb0 = kern_t + (size_t)(b * 27) * 4096 + lanelo * 64 + quad * 8;

  auto dma = [&](int p, int cur) {
    int m = p / 3, ky = p % 3;
    const bf16* src = plane0 + (size_t)m * XM_PLANE + (size_t)(y + 7 + d * (ky - 1)) * XM_ROW;
    bf16* dst = sb + cur * LBUF;
#pragma unroll
    for (int r = 0; r < 5; ++r) {
      int u0 = r * 256 + w * 64;     // wave-uniform 16B-chunk base
      __builtin_amdgcn_global_load_lds((gas1)(src + (size_t)(u0 + lane) * 8),
                                       (las3)(dst + (size_t)u0 * 8), 16, 0, 0);
    }
  };

  f32x4 acc[4][2] = {};
  dma(0, 0);
#pragma unroll
  for (int p = 0; p < 9; ++p) {
    int cur = p & 1;
    __syncthreads();                       // drains DMA(p) (in flight a full phase)
    if (p < 8) dma(p + 1, cur ^ 1);        // issue AFTER barrier: flies across compute
    int m = p / 3, ky = p % 3;
    const bf16* ap = wb0 + (size_t)(m * 9 + ky * 3) * 4096;
    bf16x8 areg[3][2][4];
#pragma unroll
    for (int kx = 0; kx < 3; ++kx)
#pragma unroll
      for (int kci = 0; kci < 2; ++kci)
#pragma unroll
        for (int mt = 0; mt < 4; ++mt)
          areg[kx][kci][mt] = *(const bf16x8*)(ap + kx * 4096 + mt * 1024 + kci * 32);
    const bf16* lb = sb + cur * LBUF + quad * 1136;
#pragma unroll
    for (int kx = 0; kx < 3; ++kx) {
      int p0 = 7 + d * (kx - 1) + w * 32 + lanelo;
#pragma unroll
      for (int kci = 0; kci < 2; ++kci) {
        const bf16* bp = lb + kci * 4544 + p0 * 8;   // ch = kci*4+quad
        bf16x8 bv[2];
#pragma unroll
        for (int nt = 0; nt < 2; ++nt) bv[nt] = *(const bf16x8*)(bp + nt * 128);
#pragma unroll
        for (int mt = 0; mt < 4; ++mt)
#pragma unroll
          for (int nt = 0; nt < 2; ++nt)
            acc[mt][nt] = __builtin_amdgcn_mfma_f32_16x16x32_bf16(areg[kx][kci][mt], bv[nt], acc[mt][nt], 0, 0, 0);
      }
    }
  }

  // epilogue -> cat chunk-major: [row y+1][di][ch][px+1][c8]
  bf16* cp = cat_p + (size_t)b * CAT_PLANE + (size_t)(y + 1) * CAT_ROW + di * CAT_DI;
#pragma unroll
  for (int mt = 0; mt < 4; ++mt) {
#pragma unroll
    for (int nt = 0; nt < 2; ++nt) {
      int px = w * 32 + nt * 16 + lanelo;
      bf16x4 v;
#pragma unroll
      for (int r = 0; r < 4; ++r) v[r] = (bf16)acc[mt][nt][r];
      *(bf16x4*)(cp + (mt * 2 + (quad >> 1)) * 1040 + (px + 1) * 8 + (quad & 1) * 4) = v;
    }
  }
}

// ------- final conv + bias + BN + ReLU: same DMA-pipelined structure ---------
// 12 phases (ky, di): stage cat slice [y+ky][di] (1040 chunks, +slack to 1280).
__global__ __launch_bounds__(256, 3) void k_final(const bf16* __restrict__ cat_p,
                                                  const bf16* __restrict__ w2_t,
                                                  const float* __restrict__ cb,
                                                  const float* __restrict__ gamma,
                                                  const float* __restrict__ beta,
                                                  const float* __restrict__ mean,
                                                  const float* __restrict__ var,
                                                  float* __restrict__ out) {
  __shared__ bf16 sb[2 * LBUF];   // 40,960 B
  int bid = blockIdx.x;            // 0..511
  int xcd = bid & 7;
  int b   = xcd >> 1;
  int y   = ((bid >> 3) << 1) | (xcd & 1);   // 0..127
  int t    = threadIdx.x;
  int lane = t & 63;
  int w    = t >> 6;
  int lanelo = lane & 15;
  int quad = lane >> 4;

  const bf16* cbase = cat_p + (size_t)b * CAT_PLANE;
  const bf16* wbase = w2_t + lanelo * 256 + quad * 8;

  auto dma = [&](int p, int cur) {
    int ky = p >> 2, dd = p & 3;
    const bf16* src = cbase + (size_t)(y + ky) * CAT_ROW + (size_t)dd * CAT_DI;
    bf16* dst = sb + cur * LBUF;
#pragma unroll
    for (int r = 0; r < 5; ++r) {
      int u0 = r * 256 + w * 64;
      __builtin_amdgcn_global_load_lds((gas1)(src + (size_t)(u0 + lane) * 8),
                                       (las3)(dst + (size_t)u0 * 8), 16, 0, 0);
    }
  };

  f32x4 acc[4][2] = {};
  dma(0, 0);
#pragma unroll
  for (int p = 0; p < 12; ++p) {
    int cur = p & 1;
    __syncthreads();
    if (p < 11) dma(p + 1, cur ^ 1);
    int ky = p >> 2, dd = p & 3;
    bf16x8 areg[3][2][4];
#pragma unroll
    for (int kx = 0; kx < 3; ++kx)
#pragma unroll
      for (int kci = 0; kci < 2; ++kci)
#pragma unroll
        for (int mt = 0; mt < 4; ++mt)
          areg[kx][kci][mt] = *(const bf16x8*)(wbase + (size_t)((ky * 3 + kx) * 64 + mt * 16) * 256
                                               + dd * 64 + kci * 32);
    const bf16* lb = sb + cur * LBUF + quad * 1040;
#pragma unroll
    for (int kx = 0; kx < 3; ++kx) {
      int p0 = w * 32 + lanelo + kx;
#pragma unroll
      for (int kci = 0; kci < 2; ++kci) {
        const bf16* bp = lb + kci * 4160 + p0 * 8;   // ch = kci*4+quad
        bf16x8 bv[2];
#pragma unroll
        for (int nt = 0; nt < 2; ++nt) bv[nt] = *(const bf16x8*)(bp + nt * 128);
#pragma unroll
        for (int mt = 0; mt < 4; ++mt)
#pragma unroll
          for (int nt = 0; nt < 2; ++nt)
            acc[mt][nt] = __builtin_amdgcn_mfma_f32_16x16x32_bf16(areg[kx][kci][mt], bv[nt], acc[mt][nt], 0, 0, 0);
      }
    }
  }

#pragma unroll
  for (int mt = 0; mt < 4; ++mt) {
#pragma unroll
    for (int nt = 0; nt < 2; ++nt) {
      int px = w * 32 + nt * 16 + lanelo;
#pragma unroll
      for (int r = 0; r < 4; ++r) {
        int oc = mt * 16 + quad * 4 + r;
        float inv = gamma[oc] * rsqrtf(var[oc] + 1e-5f);
        float v = (acc[mt][nt][r] + cb[oc]) * inv + beta[oc] - mean[oc] * inv;
        out[((size_t)(b * 64 + oc)) * HW + y * 128 + px] = fmaxf(v, 0.0f);
      }
    }
  }
}

extern "C" void kernel_launch(void* const* d_in, const int* in_sizes, int n_in,
                              void* d_out, int out_size, void* d_ws, size_t ws_size,
                              hipStream_t stream) {
  const float* x     = (const float*)d_in[0];
  const float* kern  = (const float*)d_in[1];
  const float* mw    = (const float*)d_in[2];
  const float* mb    = (const float*)d_in[3];
  const float* w2    = (const float*)d_in[4];
  const float* cb    = (const float*)d_in[5];
  const float* gamma = (const float*)d_in[6];
  const float* beta  = (const float*)d_in[7];
  const float* mean  = (const float*)d_in[8];
  const float* var   = (const float*)d_in[9];

  float* out   = (float*)d_out;
  float* masks = out + OUT_ELEMS;

  char* ws = (char*)d_ws;
  bf16* xm_p   = (bf16*)(ws);              // 30,971,904 B
  bf16* cat_p  = (bf16*)(ws + 30971904);   // 34,611,200 B (ends 65,583,104)
  bf16* kern_t = (bf16*)(ws + 65583104);   // 884,736 B (also DMA-slack target)
  bf16* w2_t   = (bf16*)(ws + 66467840);   // 294,912 B -> total 66,762,752 B
  float* part  = (float*)(ws + 30971904);  // aliases cat_p; consumed before cat writes

  k_wt<<<2304, 256, 0, stream>>>(kern, w2, kern_t, w2_t);
  k_mask1<<<dim3(128, 4, 8), 128, 0, stream>>>(x, mw, part);
  k_mask2<<<dim3(128, 4), 128, 0, stream>>>(part, mb, masks);
  k_xmt<<<dim3(142, 3, 4), 256, 0, stream>>>(x, masks, xm_p);
  k_cat_halo<<<258, 256, 0, stream>>>(cat_p);
  k_branch<<<2048, 256, 0, stream>>>(xm_p, kern_t, cat_p);
  k_final<<<512, 256, 0, stream>>>(cat_p, w2_t, cb, gamma, beta, mean, var, out);
}

// Round 9
// 404.102 us; speedup vs baseline: 1.0868x; 1.0868x over previous
//
#include <hip/hip_runtime.h>
#include <math.h>

typedef __bf16 bf16;
typedef __bf16 bf16x8 __attribute__((ext_vector_type(8)));
typedef __bf16 bf16x4 __attribute__((ext_vector_type(4)));
typedef float  f32x4  __attribute__((ext_vector_type(4)));

#define HW        16384      // 128*128
#define OUT_ELEMS 4194304    // 4*64*128*128

// padded xm: [b][m][yp=142][px142][c64] px-major; pixel (y,x) at (y+7, x+7)
#define XM_ROW    (142 * 64)
#define XM_PLANE  (142 * XM_ROW)          // 1,290,496 el
// cat: [b][row=130][di=4][px=130][c=64] px-major; pixel (y,x) at (row y+1, px x+1)
#define CAT_DI    (130 * 64)              // 8,320
#define CAT_ROW   (4 * CAT_DI)            // 33,280
#define CAT_PLANE (130 * CAT_ROW)         // 4,326,400 el

// k_branch LDS: [rr2][ch8 @ stride 1154 el][px142][c8]; 577 dw == 1 mod 32 -> 2-way (free)
#define BR_CH   1154
#define BR_RR   (8 * BR_CH)     // 9232
#define BR_BUF  (2 * BR_RR)     // 18464 el per buffer
// k_final LDS: [ch8 @ stride 1090 el][px130][c8]; 545 dw == 1 mod 32
#define FN_CH   1090
#define FN_BUF  (8 * FN_CH)     // 8720 el per buffer

// ---------------- weight transforms (fp32 -> bf16, tap-major, c innermost) ----
__global__ void k_wt(const float* __restrict__ kern, const float* __restrict__ w2,
                     bf16* __restrict__ kern_t, bf16* __restrict__ w2_t) {
  int i = blockIdx.x * 256 + threadIdx.x;
  const int N1 = 4 * 3 * 9 * 64 * 64;   // 442368
  if (i < N1) {
    int c = i & 63, o = (i >> 6) & 63, tap = (i >> 12) % 9, bm = i / 36864;
    kern_t[i] = (bf16)kern[(((bm * 64 + o) * 64 + c) * 9) + tap];
  } else {
    int j = i - N1;
    if (j < 64 * 256 * 9) {
      int ch = j & 255, oc = (j >> 8) & 63, tap = j >> 14;
      w2_t[j] = (bf16)w2[(oc * 256 + ch) * 9 + tap];
    }
  }
}

// -------- mask conv stage 1: partial logits over 8-channel groups ------------
__global__ void k_mask1(const float* __restrict__ x, const float* __restrict__ mw,
                        float* __restrict__ part) {
  int y = blockIdx.x, b = blockIdx.y, cg = blockIdx.z;
  int tx = threadIdx.x;      // 0..127
  float a0 = 0.f, a1 = 0.f, a2 = 0.f;
#pragma unroll
  for (int ci = 0; ci < 8; ++ci) {
    int c = cg * 8 + ci;
    const float* xp = x + ((size_t)(b * 64 + c)) * HW;
    const float* w0 = mw + (0 * 64 + c) * 9;
    const float* w1 = mw + (1 * 64 + c) * 9;
    const float* w2 = mw + (2 * 64 + c) * 9;
#pragma unroll
    for (int ky = 0; ky < 3; ++ky) {
      int yy = y + ky - 1;
      if ((unsigned)yy >= 128u) continue;
#pragma unroll
      for (int kx = 0; kx < 3; ++kx) {
        int xx = tx + kx - 1;
        if ((unsigned)xx >= 128u) continue;
        float xv = xp[yy * 128 + xx];
        a0 += xv * w0[ky * 3 + kx];
        a1 += xv * w1[ky * 3 + kx];
        a2 += xv * w2[ky * 3 + kx];
      }
    }
  }
  size_t base = (size_t)((b * 8 + cg) * 3) * HW + y * 128 + tx;
  part[base]          = a0;
  part[base + HW]     = a1;
  part[base + 2 * HW] = a2;
}

// -------- mask conv stage 2: reduce groups + bias + softmax ------------------
__global__ void k_mask2(const float* __restrict__ part, const float* __restrict__ mb,
                        float* __restrict__ masks) {
  int y = blockIdx.x, b = blockIdx.y;
  int tx = threadIdx.x;
  float a0 = mb[0], a1 = mb[1], a2 = mb[2];
  int off = y * 128 + tx;
#pragma unroll
  for (int cg = 0; cg < 8; ++cg) {
    size_t base = (size_t)((b * 8 + cg) * 3) * HW + off;
    a0 += part[base];
    a1 += part[base + HW];
    a2 += part[base + 2 * HW];
  }
  float mx = fmaxf(a0, fmaxf(a1, a2));
  float e0 = __expf(a0 - mx), e1 = __expf(a1 - mx), e2 = __expf(a2 - mx);
  float inv = 1.0f / (e0 + e1 + e2);
  size_t base = ((size_t)b * 3) * HW + off;
  masks[base]          = e0 * inv;
  masks[base + HW]     = e1 * inv;
  masks[base + 2 * HW] = e2 * inv;
}

// -------- xm = x * mask, NCHW fp32 -> padded NHWC(c=64) bf16, incl. halo -----
__global__ void k_xmt(const float* __restrict__ x, const float* __restrict__ masks,
                      bf16* __restrict__ xm_p) {
  int yp = blockIdx.x;  // 0..141 padded row
  int m = blockIdx.y, b = blockIdx.z;
  int t = threadIdx.x;  // 256
  bf16* prow = xm_p + (size_t)(b * 3 + m) * XM_PLANE + (size_t)yp * XM_ROW;
  bf16x8 z = {};
  if (yp < 7 || yp >= 135) {          // full halo row: 1136 chunks
#pragma unroll
    for (int i = 0; i < 5; ++i) {
      int u = i * 256 + t;
      if (u < 1136) ((bf16x8*)prow)[u] = z;
    }
    return;
  }
  // side halo: 7 px * 64c = 448 el = 56 chunks each side
  if (t < 56) ((bf16x8*)prow)[t] = z;
  else if (t < 112) ((bf16x8*)(prow + 135 * 64))[t - 56] = z;

  int y = yp - 7;
  __shared__ float tile[64 * 130];
#pragma unroll
  for (int i = 0; i < 32; ++i) {
    int u = i * 256 + t;           // 0..8191
    int c = u >> 7, xx = u & 127;
    tile[c * 130 + xx] = x[((size_t)(b * 64 + c)) * HW + y * 128 + xx];
  }
  __syncthreads();
  const float* mrow = masks + ((size_t)(b * 3 + m)) * HW + y * 128;
  bf16* orow = prow + 7 * 64;
#pragma unroll
  for (int i = 0; i < 32; ++i) {
    int u = i * 256 + t;
    int c = u & 63, xx = u >> 6;
    orow[xx * 64 + c] = (bf16)(tile[c * 130 + xx] * mrow[xx]);
  }
}

// ---------------- zero the halo of cat_p ([b][row][di][px][64]) --------------
__global__ void k_cat_halo(bf16* __restrict__ cat_p) {
  int id = blockIdx.x * 256 + threadIdx.x;
  if (id >= 4 * 16512) return;
  int plane = id / 16512, j = id % 16512;
  bf16* base = cat_p + (size_t)plane * CAT_PLANE;
  bf16x8 zv = {};
  if (j < 8320) {                         // rows 0 and 129 full: 4160 chunks each
    int row = (j / 4160) * 129;
    int off = (j % 4160) * 8;
    *(bf16x8*)(base + (size_t)row * CAT_ROW + off) = zv;
  } else {                                // rows 1..128: px 0 and 129 per di
    int k = j - 8320;                     // 0..8191 = 128 rows * 64
    int row = 1 + (k >> 6);
    int idx = k & 63;                     // di(2b) side(1b) c8(3b)
    int di = idx >> 4, side = (idx >> 3) & 1, c8 = idx & 7;
    *(bf16x8*)(base + (size_t)row * CAT_ROW + di * CAT_DI + (side * 129) * 64 + c8 * 8) = zv;
  }
}

// ------- branch convs: LDS dbuf, 1 barrier/phase, JIT areg, prefetched sreg --
// block = 256 thr (4 waves), tile = 64 o x 128 px x 2 rows. 9 phases (m,ky).
// Phase body: ds_write sreg(p) -> barrier -> [areg(p) loads; sreg(p+1) loads]
// -> compute.  sreg(p+1) flies across the whole compute; areg JIT from L1.
__global__ __launch_bounds__(256, 2) void k_branch(const bf16* __restrict__ xm_p,
                                                   const bf16* __restrict__ kern_t,
                                                   bf16* __restrict__ cat_p) {
  __shared__ bf16 sb[2 * BR_BUF];   // 73,856 B
  int bid = blockIdx.x;
  int xcd = bid & 7;
  int i   = bid >> 3;
  int b   = xcd >> 1;
  int di  = ((xcd & 1) << 1) | (i & 1);
  int y   = (i >> 1) * 2;
  int d   = 1 + 2 * di;
  int t    = threadIdx.x;
  int lane = t & 63;
  int wave = t >> 6;
  int wr   = wave >> 1;        // out-row 0/1
  int wc   = wave & 1;         // px half
  int lanelo = lane & 15;
  int quad = lane >> 4;

  const bf16* plane0 = xm_p + (size_t)(b * 3) * XM_PLANE;
  const bf16* wb0    = kern_t + (size_t)(b * 27) * 4096 + lanelo * 64 + quad * 8;

  auto srcrow = [&](int p) {
    int m = p / 3, ky = p % 3;
    return plane0 + (size_t)m * XM_PLANE + (size_t)(y + 7 + d * (ky - 1)) * XM_ROW;
  };

  bf16x8 sreg[9];
  {
    const bf16* s0 = srcrow(0);
#pragma unroll
    for (int r = 0; r < 9; ++r) {
      int u = r * 256 + t;
      if (u < 2272) sreg[r] = *(const bf16x8*)(s0 + u * 8);
    }
  }

  f32x4 acc[4][4] = {};
#pragma unroll
  for (int p = 0; p < 9; ++p) {
    int cur = p & 1;
    // stage sreg(p) into buf[cur] (chunk-major, 577-dw stride, conflict-free)
    bf16* dst = sb + cur * BR_BUF;
#pragma unroll
    for (int r = 0; r < 9; ++r) {
      int u = r * 256 + t;
      if (u < 2272) {
        int rr = (u >= 1136) ? 1 : 0;
        int v = u - rr * 1136;
        *(bf16x8*)(dst + rr * BR_RR + (v & 7) * BR_CH + (v >> 3) * 8) = sreg[r];
      }
    }
    __syncthreads();
    // areg(p): JIT loads, L1-resident (issued FIRST so their wait leaves sreg in flight)
    int m = p / 3, ky = p % 3;
    const bf16* ap = wb0 + (size_t)(m * 9 + ky * 3) * 4096;
    bf16x8 areg[3][2][4];
#pragma unroll
    for (int kx = 0; kx < 3; ++kx)
#pragma unroll
      for (int kci = 0; kci < 2; ++kci)
#pragma unroll
        for (int mt = 0; mt < 4; ++mt)
          areg[kx][kci][mt] = *(const bf16x8*)(ap + kx * 4096 + mt * 1024 + kci * 32);
    // sreg(p+1): prefetch, consumed only after next barrier -> full compute in flight
    if (p < 8) {
      const bf16* sn = srcrow(p + 1);
#pragma unroll
      for (int r = 0; r < 9; ++r) {
        int u = r * 256 + t;
        if (u < 2272) sreg[r] = *(const bf16x8*)(sn + u * 8);
      }
    }
    // compute on buf[cur]
    const bf16* bufb = sb + cur * BR_BUF + wr * BR_RR + quad * BR_CH;
#pragma unroll
    for (int kx = 0; kx < 3; ++kx) {
      int p0 = 7 + d * (kx - 1) + wc * 64 + lanelo;
#pragma unroll
      for (int kci = 0; kci < 2; ++kci) {
        const bf16* bp = bufb + kci * (4 * BR_CH) + p0 * 8;
        bf16x8 bv[4];
#pragma unroll
        for (int nt = 0; nt < 4; ++nt) bv[nt] = *(const bf16x8*)(bp + nt * 128);
#pragma unroll
        for (int mt = 0; mt < 4; ++mt)
#pragma unroll
          for (int nt = 0; nt < 4; ++nt)
            acc[mt][nt] = __builtin_amdgcn_mfma_f32_16x16x32_bf16(areg[kx][kci][mt], bv[nt], acc[mt][nt], 0, 0, 0);
      }
    }
  }

  // epilogue: cat[b][y+wr+1][di][px+1][o]
  bf16* cp = cat_p + (size_t)b * CAT_PLANE + (size_t)(y + wr + 1) * CAT_ROW + di * CAT_DI;
#pragma unroll
  for (int mt = 0; mt < 4; ++mt) {
#pragma unroll
    for (int nt = 0; nt < 4; ++nt) {
      int px = wc * 64 + nt * 16 + lanelo;
      bf16x4 v;
#pragma unroll
      for (int r = 0; r < 4; ++r) v[r] = (bf16)acc[mt][nt][r];
      *(bf16x4*)(cp + (size_t)(px + 1) * 64 + mt * 16 + quad * 4) = v;
    }
  }
}

// ------- final conv + bias + BN + ReLU: 1-row tile, LDS dbuf pipelined -------
// block = 256 thr (4 waves on px quarters), tile = 64 o x 128 px x 1 row.
// 12 phases (ky, di): stage cat slice [y+ky][di] (1040 chunks).
__global__ __launch_bounds__(256, 2) void k_final(const bf16* __restrict__ cat_p,
                                                  const bf16* __restrict__ w2_t,
                                                  const float* __restrict__ cb,
                                                  const float* __restrict__ gamma,
                                                  const float* __restrict__ beta,
                                                  const float* __restrict__ mean,
                                                  const float* __restrict__ var,
                                                  float* __restrict__ out) {
  __shared__ bf16 sb[2 * FN_BUF];   // 34,880 B
  int bid = blockIdx.x;              // 0..511
  int xcd = bid & 7;
  int b   = xcd >> 1;
  int y   = ((bid >> 3) << 1) | (xcd & 1);   // 0..127
  int t    = threadIdx.x;
  int lane = t & 63;
  int w    = t >> 6;           // px quarter
  int lanelo = lane & 15;
  int quad = lane >> 4;

  const bf16* cbase = cat_p + (size_t)b * CAT_PLANE;
  const bf16* wbase = w2_t + lanelo * 256 + quad * 8;

  auto srcrow = [&](int p) {
    int ky = p >> 2, dd = p & 3;
    return cbase + (size_t)(y + ky) * CAT_ROW + (size_t)dd * CAT_DI;
  };

  bf16x8 sreg[5];
  {
    const bf16* s0 = srcrow(0);
#pragma unroll
    for (int r = 0; r < 5; ++r) {
      int u = r * 256 + t;
      if (u < 1040) sreg[r] = *(const bf16x8*)(s0 + u * 8);
    }
  }

  f32x4 acc[4][2] = {};
#pragma unroll
  for (int p = 0; p < 12; ++p) {
    int cur = p & 1;
    bf16* dst = sb + cur * FN_BUF;
#pragma unroll
    for (int r = 0; r < 5; ++r) {
      int u = r * 256 + t;
      if (u < 1040) *(bf16x8*)(dst + (u & 7) * FN_CH + (u >> 3) * 8) = sreg[r];
    }
    __syncthreads();
    int ky = p >> 2, dd = p & 3;
    bf16x8 areg[3][2][4];
#pragma unroll
    for (int kx = 0; kx < 3; ++kx)
#pragma unroll
      for (int kci = 0; kci < 2; ++kci)
#pragma unroll
        for (int mt = 0; mt < 4; ++mt)
          areg[kx][kci][mt] = *(const bf16x8*)(wbase + (size_t)((ky * 3 + kx) * 64 + mt * 16) * 256
                                               + dd * 64 + kci * 32);
    if (p < 11) {
      const bf16* sn = srcrow(p + 1);
#pragma unroll
      for (int r = 0; r < 5; ++r) {
        int u = r * 256 + t;
        if (u < 1040) sreg[r] = *(const bf16x8*)(sn + u * 8);
      }
    }
    const bf16* bufb = sb + cur * FN_BUF + quad * FN_CH;
#pragma unroll
    for (int kx = 0; kx < 3; ++kx) {
      int p0 = w * 32 + lanelo + kx;
#pragma unroll
      for (int kci = 0; kci < 2; ++kci) {
        const bf16* bp = bufb + kci * (4 * FN_CH) + p0 * 8;
        bf16x8 bv[2];
#pragma unroll
        for (int nt = 0; nt < 2; ++nt) bv[nt] = *(const bf16x8*)(bp + nt * 128);
#pragma unroll
        for (int mt = 0; mt < 4; ++mt)
#pragma unroll
          for (int nt = 0; nt < 2; ++nt)
            acc[mt][nt] = __builtin_amdgcn_mfma_f32_16x16x32_bf16(areg[kx][kci][mt], bv[nt], acc[mt][nt], 0, 0, 0);
      }
    }
  }

#pragma unroll
  for (int mt = 0; mt < 4; ++mt) {
#pragma unroll
    for (int nt = 0; nt < 2; ++nt) {
      int px = w * 32 + nt * 16 + lanelo;
#pragma unroll
      for (int r = 0; r < 4; ++r) {
        int oc = mt * 16 + quad * 4 + r;
        float inv = gamma[oc] * rsqrtf(var[oc] + 1e-5f);
        float v = (acc[mt][nt][r] + cb[oc]) * inv + beta[oc] - mean[oc] * inv;
        out[((size_t)(b * 64 + oc)) * HW + y * 128 + px] = fmaxf(v, 0.0f);
      }
    }
  }
}

extern "C" void kernel_launch(void* const* d_in, const int* in_sizes, int n_in,
                              void* d_out, int out_size, void* d_ws, size_t ws_size,
                              hipStream_t stream) {
  const float* x     = (const float*)d_in[0];
  const float* kern  = (const float*)d_in[1];
  const float* mw    = (const float*)d_in[2];
  const float* mb    = (const float*)d_in[3];
  const float* w2    = (const float*)d_in[4];
  const float* cb    = (const float*)d_in[5];
  const float* gamma = (const float*)d_in[6];
  const float* beta  = (const float*)d_in[7];
  const float* mean  = (const float*)d_in[8];
  const float* var   = (const float*)d_in[9];

  float* out   = (float*)d_out;
  float* masks = out + OUT_ELEMS;

  char* ws = (char*)d_ws;
  bf16* xm_p   = (bf16*)(ws);              // 30,971,904 B
  bf16* cat_p  = (bf16*)(ws + 30971904);   // 34,611,200 B (ends 65,583,104)
  bf16* kern_t = (bf16*)(ws + 65583104);   // 884,736 B
  bf16* w2_t   = (bf16*)(ws + 66467840);   // 294,912 B -> total 66,762,752 B
  float* part  = (float*)(ws + 30971904);  // aliases cat_p; consumed before cat writes

  k_wt<<<2304, 256, 0, stream>>>(kern, w2, kern_t, w2_t);
  k_mask1<<<dim3(128, 4, 8), 128, 0, stream>>>(x, mw, part);
  k_mask2<<<dim3(128, 4), 128, 0, stream>>>(part, mb, masks);
  k_xmt<<<dim3(142, 3, 4), 256, 0, stream>>>(x, masks, xm_p);
  k_cat_halo<<<258, 256, 0, stream>>>(cat_p);
  k_branch<<<1024, 256, 0, stream>>>(xm_p, kern_t, cat_p);
  k_final<<<512, 256, 0, stream>>>(cat_p, w2_t, cb, gamma, beta, mean, var, out);
}

// Round 10
// 389.292 us; speedup vs baseline: 1.1281x; 1.0380x over previous
//
#include <hip/hip_runtime.h>
#include <math.h>

typedef __bf16 bf16;
typedef __bf16 bf16x8 __attribute__((ext_vector_type(8)));
typedef __bf16 bf16x4 __attribute__((ext_vector_type(4)));
typedef float  f32x4  __attribute__((ext_vector_type(4)));

#define HW        16384      // 128*128
#define OUT_ELEMS 4194304    // 4*64*128*128

// padded xm: [b][m][yp=142][px142][c64] px-major; pixel (y,x) at (y+7, x+7)
#define XM_ROW    (142 * 64)
#define XM_PLANE  (142 * XM_ROW)          // 1,290,496 el
// cat: [b][row=130][di=4][px=130][c=64] px-major; pixel (y,x) at (row y+1, px x+1)
#define CAT_DI    (130 * 64)              // 8,320
#define CAT_ROW   (4 * CAT_DI)            // 33,280
#define CAT_PLANE (130 * CAT_ROW)         // 4,326,400 el

// k_branch LDS: [rr2][ch8 @ stride 1154 el][px142][c8]; 577 dw == 1 mod 32 -> 2-way (free)
#define BR_CH   1154
#define BR_RR   (8 * BR_CH)     // 9232 el; single buffer = 2*BR_RR = 36,928 B
// k_final LDS: [ch8 @ stride 1090 el][px130][c8]; 545 dw == 1 mod 32
#define FN_CH   1090
#define FN_BUF  (8 * FN_CH)     // 8720 el = 17,440 B

// ---------------- weight transforms (fp32 -> bf16, tap-major, c innermost) ----
__global__ void k_wt(const float* __restrict__ kern, const float* __restrict__ w2,
                     bf16* __restrict__ kern_t, bf16* __restrict__ w2_t) {
  int i = blockIdx.x * 256 + threadIdx.x;
  const int N1 = 4 * 3 * 9 * 64 * 64;   // 442368
  if (i < N1) {
    int c = i & 63, o = (i >> 6) & 63, tap = (i >> 12) % 9, bm = i / 36864;
    kern_t[i] = (bf16)kern[(((bm * 64 + o) * 64 + c) * 9) + tap];
  } else {
    int j = i - N1;
    if (j < 64 * 256 * 9) {
      int ch = j & 255, oc = (j >> 8) & 63, tap = j >> 14;
      w2_t[j] = (bf16)w2[(oc * 256 + ch) * 9 + tap];
    }
  }
}

// -------- mask conv stage 1: partial logits over 8-channel groups ------------
__global__ void k_mask1(const float* __restrict__ x, const float* __restrict__ mw,
                        float* __restrict__ part) {
  int y = blockIdx.x, b = blockIdx.y, cg = blockIdx.z;
  int tx = threadIdx.x;      // 0..127
  float a0 = 0.f, a1 = 0.f, a2 = 0.f;
#pragma unroll
  for (int ci = 0; ci < 8; ++ci) {
    int c = cg * 8 + ci;
    const float* xp = x + ((size_t)(b * 64 + c)) * HW;
    const float* w0 = mw + (0 * 64 + c) * 9;
    const float* w1 = mw + (1 * 64 + c) * 9;
    const float* w2 = mw + (2 * 64 + c) * 9;
#pragma unroll
    for (int ky = 0; ky < 3; ++ky) {
      int yy = y + ky - 1;
      if ((unsigned)yy >= 128u) continue;
#pragma unroll
      for (int kx = 0; kx < 3; ++kx) {
        int xx = tx + kx - 1;
        if ((unsigned)xx >= 128u) continue;
        float xv = xp[yy * 128 + xx];
        a0 += xv * w0[ky * 3 + kx];
        a1 += xv * w1[ky * 3 + kx];
        a2 += xv * w2[ky * 3 + kx];
      }
    }
  }
  size_t base = (size_t)((b * 8 + cg) * 3) * HW + y * 128 + tx;
  part[base]          = a0;
  part[base + HW]     = a1;
  part[base + 2 * HW] = a2;
}

// -------- mask conv stage 2: reduce groups + bias + softmax ------------------
__global__ void k_mask2(const float* __restrict__ part, const float* __restrict__ mb,
                        float* __restrict__ masks) {
  int y = blockIdx.x, b = blockIdx.y;
  int tx = threadIdx.x;
  float a0 = mb[0], a1 = mb[1], a2 = mb[2];
  int off = y * 128 + tx;
#pragma unroll
  for (int cg = 0; cg < 8; ++cg) {
    size_t base = (size_t)((b * 8 + cg) * 3) * HW + off;
    a0 += part[base];
    a1 += part[base + HW];
    a2 += part[base + 2 * HW];
  }
  float mx = fmaxf(a0, fmaxf(a1, a2));
  float e0 = __expf(a0 - mx), e1 = __expf(a1 - mx), e2 = __expf(a2 - mx);
  float inv = 1.0f / (e0 + e1 + e2);
  size_t base = ((size_t)b * 3) * HW + off;
  masks[base]          = e0 * inv;
  masks[base + HW]     = e1 * inv;
  masks[base + 2 * HW] = e2 * inv;
}

// -------- xm = x * mask, NCHW fp32 -> padded NHWC(c=64) bf16, incl. halo -----
__global__ void k_xmt(const float* __restrict__ x, const float* __restrict__ masks,
                      bf16* __restrict__ xm_p) {
  int yp = blockIdx.x;  // 0..141 padded row
  int m = blockIdx.y, b = blockIdx.z;
  int t = threadIdx.x;  // 256
  bf16* prow = xm_p + (size_t)(b * 3 + m) * XM_PLANE + (size_t)yp * XM_ROW;
  bf16x8 z = {};
  if (yp < 7 || yp >= 135) {          // full halo row: 1136 chunks
#pragma unroll
    for (int i = 0; i < 5; ++i) {
      int u = i * 256 + t;
      if (u < 1136) ((bf16x8*)prow)[u] = z;
    }
    return;
  }
  // side halo: 7 px * 64c = 448 el = 56 chunks each side
  if (t < 56) ((bf16x8*)prow)[t] = z;
  else if (t < 112) ((bf16x8*)(prow + 135 * 64))[t - 56] = z;

  int y = yp - 7;
  __shared__ float tile[64 * 130];
#pragma unroll
  for (int i = 0; i < 32; ++i) {
    int u = i * 256 + t;           // 0..8191
    int c = u >> 7, xx = u & 127;
    tile[c * 130 + xx] = x[((size_t)(b * 64 + c)) * HW + y * 128 + xx];
  }
  __syncthreads();
  const float* mrow = masks + ((size_t)(b * 3 + m)) * HW + y * 128;
  bf16* orow = prow + 7 * 64;
#pragma unroll
  for (int i = 0; i < 32; ++i) {
    int u = i * 256 + t;
    int c = u & 63, xx = u >> 6;
    orow[xx * 64 + c] = (bf16)(tile[c * 130 + xx] * mrow[xx]);
  }
}

// ---------------- zero the halo of cat_p ([b][row][di][px][64]) --------------
__global__ void k_cat_halo(bf16* __restrict__ cat_p) {
  int id = blockIdx.x * 256 + threadIdx.x;
  if (id >= 4 * 16512) return;
  int plane = id / 16512, j = id % 16512;
  bf16* base = cat_p + (size_t)plane * CAT_PLANE;
  bf16x8 zv = {};
  if (j < 8320) {                         // rows 0 and 129 full: 4160 chunks each
    int row = (j / 4160) * 129;
    int off = (j % 4160) * 8;
    *(bf16x8*)(base + (size_t)row * CAT_ROW + off) = zv;
  } else {                                // rows 1..128: px 0 and 129 per di
    int k = j - 8320;                     // 0..8191 = 128 rows * 64
    int row = 1 + (k >> 6);
    int idx = k & 63;                     // di(2b) side(1b) c8(3b)
    int di = idx >> 4, side = (idx >> 3) & 1, c8 = idx & 7;
    *(bf16x8*)(base + (size_t)row * CAT_ROW + di * CAT_DI + (side * 129) * 64 + c8 * 8) = zv;
  }
}

// ------- branch convs: R6 skeleton + conflict-free chunk-major LDS -----------
// block = 256 thr (4 waves), tile = 64 o x 128 px x 2 rows. 9 phases (m,ky).
// Phase: areg(p) loads -> sync -> ds_write sreg(p) -> issue sreg(p+1) -> sync
// -> compute.  Single LDS buffer (2 barriers make reuse safe).
__global__ __launch_bounds__(256, 2) void k_branch(const bf16* __restrict__ xm_p,
                                                   const bf16* __restrict__ kern_t,
                                                   bf16* __restrict__ cat_p) {
  __shared__ bf16 sb[2 * BR_RR];   // 36,928 B
  int bid = blockIdx.x;
  int xcd = bid & 7;
  int i   = bid >> 3;
  int b   = xcd >> 1;
  int di  = ((xcd & 1) << 1) | (i & 1);
  int y   = (i >> 1) * 2;
  int d   = 1 + 2 * di;
  int t    = threadIdx.x;
  int lane = t & 63;
  int wave = t >> 6;
  int wr   = wave >> 1;        // out-row 0/1
  int wc   = wave & 1;         // px half
  int lanelo = lane & 15;
  int quad = lane >> 4;

  const bf16* plane0 = xm_p + (size_t)(b * 3) * XM_PLANE;
  const bf16* wb0    = kern_t + (size_t)(b * 27) * 4096 + lanelo * 64 + quad * 8;

  auto srcrow = [&](int p) {
    int m = p / 3, ky = p % 3;
    return plane0 + (size_t)m * XM_PLANE + (size_t)(y + 7 + d * (ky - 1)) * XM_ROW;
  };

  bf16x8 sreg[9];
  {
    const bf16* s0 = srcrow(0);
#pragma unroll
    for (int r = 0; r < 9; ++r) {
      int u = r * 256 + t;
      if (u < 2272) sreg[r] = *(const bf16x8*)(s0 + u * 8);
    }
  }

  f32x4 acc[4][4] = {};
#pragma unroll
  for (int p = 0; p < 9; ++p) {
    // areg(p): loaded BEFORE the barriers (overlaps barrier arrival skew)
    int m = p / 3, ky = p % 3;
    const bf16* ap = wb0 + (size_t)(m * 9 + ky * 3) * 4096;
    bf16x8 areg[3][2][4];
#pragma unroll
    for (int kx = 0; kx < 3; ++kx)
#pragma unroll
      for (int kci = 0; kci < 2; ++kci)
#pragma unroll
        for (int mt = 0; mt < 4; ++mt)
          areg[kx][kci][mt] = *(const bf16x8*)(ap + kx * 4096 + mt * 1024 + kci * 32);

    __syncthreads();   // previous phase's LDS reads done
    // stage sreg(p): chunk-major, 577-dw stride (conflict-free)
#pragma unroll
    for (int r = 0; r < 9; ++r) {
      int u = r * 256 + t;
      if (u < 2272) {
        int rr = (u >= 1136) ? 1 : 0;
        int v = u - rr * 1136;
        *(bf16x8*)(sb + rr * BR_RR + (v & 7) * BR_CH + (v >> 3) * 8) = sreg[r];
      }
    }
    // issue sreg(p+1)
    if (p < 8) {
      const bf16* sn = srcrow(p + 1);
#pragma unroll
      for (int r = 0; r < 9; ++r) {
        int u = r * 256 + t;
        if (u < 2272) sreg[r] = *(const bf16x8*)(sn + u * 8);
      }
    }
    __syncthreads();   // staged data visible
    // compute
    const bf16* bufb = sb + wr * BR_RR + quad * BR_CH;
#pragma unroll
    for (int kx = 0; kx < 3; ++kx) {
      int p0 = 7 + d * (kx - 1) + wc * 64 + lanelo;
#pragma unroll
      for (int kci = 0; kci < 2; ++kci) {
        const bf16* bp = bufb + kci * (4 * BR_CH) + p0 * 8;
        bf16x8 bv[4];
#pragma unroll
        for (int nt = 0; nt < 4; ++nt) bv[nt] = *(const bf16x8*)(bp + nt * 128);
#pragma unroll
        for (int mt = 0; mt < 4; ++mt)
#pragma unroll
          for (int nt = 0; nt < 4; ++nt)
            acc[mt][nt] = __builtin_amdgcn_mfma_f32_16x16x32_bf16(areg[kx][kci][mt], bv[nt], acc[mt][nt], 0, 0, 0);
      }
    }
  }

  // epilogue: cat[b][y+wr+1][di][px+1][o]
  bf16* cp = cat_p + (size_t)b * CAT_PLANE + (size_t)(y + wr + 1) * CAT_ROW + di * CAT_DI;
#pragma unroll
  for (int mt = 0; mt < 4; ++mt) {
#pragma unroll
    for (int nt = 0; nt < 4; ++nt) {
      int px = wc * 64 + nt * 16 + lanelo;
      bf16x4 v;
#pragma unroll
      for (int r = 0; r < 4; ++r) v[r] = (bf16)acc[mt][nt][r];
      *(bf16x4*)(cp + (size_t)(px + 1) * 64 + mt * 16 + quad * 4) = v;
    }
  }
}

// ------- final conv + bias + BN + ReLU: R6 skeleton, 1-row tile --------------
// block = 256 thr (4 waves on px quarters), tile = 64 o x 128 px x 1 row.
// 12 phases (ky, di): stage cat slice [y+ky][di] (1040 chunks, conflict-free).
__global__ __launch_bounds__(256, 2) void k_final(const bf16* __restrict__ cat_p,
                                                  const bf16* __restrict__ w2_t,
                                                  const float* __restrict__ cb,
                                                  const float* __restrict__ gamma,
                                                  const float* __restrict__ beta,
                                                  const float* __restrict__ mean,
                                                  const float* __restrict__ var,
                                                  float* __restrict__ out) {
  __shared__ bf16 sb[FN_BUF];   // 17,440 B
  int bid = blockIdx.x;          // 0..511
  int xcd = bid & 7;
  int b   = xcd >> 1;
  int y   = ((bid >> 3) << 1) | (xcd & 1);   // 0..127
  int t    = threadIdx.x;
  int lane = t & 63;
  int w    = t >> 6;           // px quarter
  int lanelo = lane & 15;
  int quad = lane >> 4;

  const bf16* cbase = cat_p + (size_t)b * CAT_PLANE;
  const bf16* wbase = w2_t + lanelo * 256 + quad * 8;

  auto srcrow = [&](int p) {
    int ky = p >> 2, dd = p & 3;
    return cbase + (size_t)(y + ky) * CAT_ROW + (size_t)dd * CAT_DI;
  };

  bf16x8 sreg[5];
  {
    const bf16* s0 = srcrow(0);
#pragma unroll
    for (int r = 0; r < 5; ++r) {
      int u = r * 256 + t;
      if (u < 1040) sreg[r] = *(const bf16x8*)(s0 + u * 8);
    }
  }

  f32x4 acc[4][2] = {};
#pragma unroll
  for (int p = 0; p < 12; ++p) {
    int ky = p >> 2, dd = p & 3;
    bf16x8 areg[3][2][4];
#pragma unroll
    for (int kx = 0; kx < 3; ++kx)
#pragma unroll
      for (int kci = 0; kci < 2; ++kci)
#pragma unroll
        for (int mt = 0; mt < 4; ++mt)
          areg[kx][kci][mt] = *(const bf16x8*)(wbase + (size_t)((ky * 3 + kx) * 64 + mt * 16) * 256
                                               + dd * 64 + kci * 32);
    __syncthreads();
#pragma unroll
    for (int r = 0; r < 5; ++r) {
      int u = r * 256 + t;
      if (u < 1040) *(bf16x8*)(sb + (u & 7) * FN_CH + (u >> 3) * 8) = sreg[r];
    }
    if (p < 11) {
      const bf16* sn = srcrow(p + 1);
#pragma unroll
      for (int r = 0; r < 5; ++r) {
        int u = r * 256 + t;
        if (u < 1040) sreg[r] = *(const bf16x8*)(sn + u * 8);
      }
    }
    __syncthreads();
    const bf16* bufb = sb + quad * FN_CH;
#pragma unroll
    for (int kx = 0; kx < 3; ++kx) {
      int p0 = w * 32 + lanelo + kx;
#pragma unroll
      for (int kci = 0; kci < 2; ++kci) {
        const bf16* bp = bufb + kci * (4 * FN_CH) + p0 * 8;
        bf16x8 bv[2];
#pragma unroll
        for (int nt = 0; nt < 2; ++nt) bv[nt] = *(const bf16x8*)(bp + nt * 128);
#pragma unroll
        for (int mt = 0; mt < 4; ++mt)
#pragma unroll
          for (int nt = 0; nt < 2; ++nt)
            acc[mt][nt] = __builtin_amdgcn_mfma_f32_16x16x32_bf16(areg[kx][kci][mt], bv[nt], acc[mt][nt], 0, 0, 0);
      }
    }
  }

#pragma unroll
  for (int mt = 0; mt < 4; ++mt) {
#pragma unroll
    for (int nt = 0; nt < 2; ++nt) {
      int px = w * 32 + nt * 16 + lanelo;
#pragma unroll
      for (int r = 0; r < 4; ++r) {
        int oc = mt * 16 + quad * 4 + r;
        float inv = gamma[oc] * rsqrtf(var[oc] + 1e-5f);
        float v = (acc[mt][nt][r] + cb[oc]) * inv + beta[oc] - mean[oc] * inv;
        out[((size_t)(b * 64 + oc)) * HW + y * 128 + px] = fmaxf(v, 0.0f);
      }
    }
  }
}

extern "C" void kernel_launch(void* const* d_in, const int* in_sizes, int n_in,
                              void* d_out, int out_size, void* d_ws, size_t ws_size,
                              hipStream_t stream) {
  const float* x     = (const float*)d_in[0];
  const float* kern  = (const float*)d_in[1];
  const float* mw    = (const float*)d_in[2];
  const float* mb    = (const float*)d_in[3];
  const float* w2    = (const float*)d_in[4];
  const float* cb    = (const float*)d_in[5];
  const float* gamma = (const float*)d_in[6];
  const float* beta  = (const float*)d_in[7];
  const float* mean  = (const float*)d_in[8];
  const float* var   = (const float*)d_in[9];

  float* out   = (float*)d_out;
  float* masks = out + OUT_ELEMS;

  char* ws = (char*)d_ws;
  bf16* xm_p   = (bf16*)(ws);              // 30,971,904 B
  bf16* cat_p  = (bf16*)(ws + 30971904);   // 34,611,200 B (ends 65,583,104)
  bf16* kern_t = (bf16*)(ws + 65583104);   // 884,736 B
  bf16* w2_t   = (bf16*)(ws + 66467840);   // 294,912 B -> total 66,762,752 B
  float* part  = (float*)(ws + 30971904);  // aliases cat_p; consumed before cat writes

  k_wt<<<2304, 256, 0, stream>>>(kern, w2, kern_t, w2_t);
  k_mask1<<<dim3(128, 4, 8), 128, 0, stream>>>(x, mw, part);
  k_mask2<<<dim3(128, 4), 128, 0, stream>>>(part, mb, masks);
  k_xmt<<<dim3(142, 3, 4), 256, 0, stream>>>(x, masks, xm_p);
  k_cat_halo<<<258, 256, 0, stream>>>(cat_p);
  k_branch<<<1024, 256, 0, stream>>>(xm_p, kern_t, cat_p);
  k_final<<<512, 256, 0, stream>>>(cat_p, w2_t, cb, gamma, beta, mean, var, out);
}

// Round 11
// 322.131 us; speedup vs baseline: 1.3633x; 1.2085x over previous
//
#include <hip/hip_runtime.h>
#include <math.h>

typedef __bf16 bf16;
typedef __bf16 bf16x8 __attribute__((ext_vector_type(8)));
typedef __bf16 bf16x4 __attribute__((ext_vector_type(4)));
typedef float  f32x4  __attribute__((ext_vector_type(4)));

#define HW        16384      // 128*128
#define OUT_ELEMS 4194304    // 4*64*128*128

// xm: [b][m][row142][cc8][px142][c8] chunk-major rows; pixel (y,x) at row y+7, px x+7
#define XM_ROW    9088                    // 142*64 el per row (1136 16B-chunks)
#define XM_PLANE  (142 * XM_ROW)          // 1,290,496 el
// cat: [b][row130][di4][cc8][px130][c8]; pixel (y,x) at row y+1, px x+1
#define CAT_DI    8320                    // 130*64 el (1040 chunks)
#define CAT_ROW   (4 * CAT_DI)            // 33,280
#define CAT_PLANE (130 * CAT_ROW)         // 4,326,400 el

// k_branch LDS buffer: 2304 chunks (2 rows = 2272 + 32 slack) = 18,432 el
#define BR_BUF 18432
// k_final LDS buffer: 2 regions x 1152 chunks (1040 + 112 slack) = 18,432 el
#define FN_REG 9216
#define FN_BUF 18432

typedef const __attribute__((address_space(1))) void* gas1;
typedef __attribute__((address_space(3))) void* las3;

// ---------------- weight transforms (fp32 -> bf16, tap-major, c innermost) ----
__global__ void k_wt(const float* __restrict__ kern, const float* __restrict__ w2,
                     bf16* __restrict__ kern_t, bf16* __restrict__ w2_t) {
  int i = blockIdx.x * 256 + threadIdx.x;
  const int N1 = 4 * 3 * 9 * 64 * 64;   // 442368
  if (i < N1) {
    int c = i & 63, o = (i >> 6) & 63, tap = (i >> 12) % 9, bm = i / 36864;
    kern_t[i] = (bf16)kern[(((bm * 64 + o) * 64 + c) * 9) + tap];
  } else {
    int j = i - N1;
    if (j < 64 * 256 * 9) {
      int ch = j & 255, oc = (j >> 8) & 63, tap = j >> 14;
      w2_t[j] = (bf16)w2[(oc * 256 + ch) * 9 + tap];
    }
  }
}

// -------- mask conv stage 1: partial logits over 8-channel groups ------------
__global__ void k_mask1(const float* __restrict__ x, const float* __restrict__ mw,
                        float* __restrict__ part) {
  int y = blockIdx.x, b = blockIdx.y, cg = blockIdx.z;
  int tx = threadIdx.x;      // 0..127
  float a0 = 0.f, a1 = 0.f, a2 = 0.f;
#pragma unroll
  for (int ci = 0; ci < 8; ++ci) {
    int c = cg * 8 + ci;
    const float* xp = x + ((size_t)(b * 64 + c)) * HW;
    const float* w0 = mw + (0 * 64 + c) * 9;
    const float* w1 = mw + (1 * 64 + c) * 9;
    const float* w2 = mw + (2 * 64 + c) * 9;
#pragma unroll
    for (int ky = 0; ky < 3; ++ky) {
      int yy = y + ky - 1;
      if ((unsigned)yy >= 128u) continue;
#pragma unroll
      for (int kx = 0; kx < 3; ++kx) {
        int xx = tx + kx - 1;
        if ((unsigned)xx >= 128u) continue;
        float xv = xp[yy * 128 + xx];
        a0 += xv * w0[ky * 3 + kx];
        a1 += xv * w1[ky * 3 + kx];
        a2 += xv * w2[ky * 3 + kx];
      }
    }
  }
  size_t base = (size_t)((b * 8 + cg) * 3) * HW + y * 128 + tx;
  part[base]          = a0;
  part[base + HW]     = a1;
  part[base + 2 * HW] = a2;
}

// -------- mask conv stage 2: reduce groups + bias + softmax ------------------
__global__ void k_mask2(const float* __restrict__ part, const float* __restrict__ mb,
                        float* __restrict__ masks) {
  int y = blockIdx.x, b = blockIdx.y;
  int tx = threadIdx.x;
  float a0 = mb[0], a1 = mb[1], a2 = mb[2];
  int off = y * 128 + tx;
#pragma unroll
  for (int cg = 0; cg < 8; ++cg) {
    size_t base = (size_t)((b * 8 + cg) * 3) * HW + off;
    a0 += part[base];
    a1 += part[base + HW];
    a2 += part[base + 2 * HW];
  }
  float mx = fmaxf(a0, fmaxf(a1, a2));
  float e0 = __expf(a0 - mx), e1 = __expf(a1 - mx), e2 = __expf(a2 - mx);
  float inv = 1.0f / (e0 + e1 + e2);
  size_t base = ((size_t)b * 3) * HW + off;
  masks[base]          = e0 * inv;
  masks[base + HW]     = e1 * inv;
  masks[base + 2 * HW] = e2 * inv;
}

// -------- xm = x * mask -> chunk-major padded rows, incl. halo zeroing -------
__global__ void k_xmt(const float* __restrict__ x, const float* __restrict__ masks,
                      bf16* __restrict__ xm_p) {
  int yp = blockIdx.x;  // 0..141 padded row
  int m = blockIdx.y, b = blockIdx.z;
  int t = threadIdx.x;  // 256
  bf16* prow = xm_p + (size_t)(b * 3 + m) * XM_PLANE + (size_t)yp * XM_ROW;
  bf16x8 z = {};
  if (yp < 7 || yp >= 135) {          // full halo row: 1136 16B-chunks
#pragma unroll
    for (int i = 0; i < 5; ++i) {
      int u = i * 256 + t;
      if (u < 1136) *(bf16x8*)(prow + u * 8) = z;
    }
    return;
  }
  // side halos: per cc-chunk, px 0..6 (el 0..55) and px 135..141 (el 1080..1135)
  if (t < 112) {
    int ch = t / 14, rem = t % 14, side = rem / 7, j = rem % 7;
    *(bf16x8*)(prow + ch * 1136 + side * 1080 + j * 8) = z;
  }

  int y = yp - 7;
  __shared__ float tile[64 * 130];
#pragma unroll
  for (int i = 0; i < 32; ++i) {
    int u = i * 256 + t;           // 0..8191
    int c = u >> 7, xx = u & 127;
    tile[c * 130 + xx] = x[((size_t)(b * 64 + c)) * HW + y * 128 + xx];
  }
  __syncthreads();
  const float* mrow = masks + ((size_t)(b * 3 + m)) * HW + y * 128;
#pragma unroll
  for (int i = 0; i < 32; ++i) {
    int u = i * 256 + t;
    int c = u & 63, xx = u >> 6;
    prow[(c >> 3) * 1136 + (xx + 7) * 8 + (c & 7)] = (bf16)(tile[c * 130 + xx] * mrow[xx]);
  }
}

// ---------------- zero the halo of cat_p (chunk-major slices) ----------------
__global__ void k_cat_halo(bf16* __restrict__ cat_p) {
  int id = blockIdx.x * 256 + threadIdx.x;
  if (id >= 4 * 16512) return;
  int plane = id / 16512, j = id % 16512;
  bf16* base = cat_p + (size_t)plane * CAT_PLANE;
  bf16x8 zv = {};
  if (j < 8320) {                         // rows 0 and 129 full: 4160 chunks each
    int row = (j / 4160) * 129;
    int off = (j % 4160) * 8;
    *(bf16x8*)(base + (size_t)row * CAT_ROW + off) = zv;
  } else {                                // rows 1..128: px 0 and 129 per (di,cc)
    int k = j - 8320;                     // 0..8191 = 128 rows * 64
    int row = 1 + (k >> 6);
    int idx = k & 63;                     // di(2b) ch(3b) side(1b)
    int di = idx >> 4, ch = (idx >> 1) & 7, side = idx & 1;
    *(bf16x8*)(base + (size_t)row * CAT_ROW + di * CAT_DI + ch * 1040 + side * 129 * 8) = zv;
  }
}

// ------- branch convs: B via global_load_lds dbuf, A JIT from L1 -------------
// block = 256 thr (4 waves: wr x wc), tile = 64o x 128px x 2 rows. 9 phases (m,ky).
// Phase: areg(p) issue (vmem FIRST) -> DMA(p+1) issue -> compute -> barrier.
// FIFO: waiting on areg leaves the later DMA in flight across all of compute;
// the barrier's vmcnt(0) then finds DMA(p+1) already landed.
__global__ __launch_bounds__(256, 2) void k_branch(const bf16* __restrict__ xm_p,
                                                   const bf16* __restrict__ kern_t,
                                                   bf16* __restrict__ cat_p) {
  __shared__ bf16 sb[2 * BR_BUF];   // 73,728 B
  int bid = blockIdx.x;
  int xcd = bid & 7;
  int i   = bid >> 3;
  int b   = xcd >> 1;
  int di  = ((xcd & 1) << 1) | (i & 1);
  int y   = (i >> 1) * 2;
  int d   = 1 + 2 * di;
  int t    = threadIdx.x;
  int lane = t & 63;
  int wave = t >> 6;
  int wr   = wave >> 1;        // out-row 0/1
  int wc   = wave & 1;         // px half
  int lanelo = lane & 15;
  int quad = lane >> 4;

  const bf16* plane0 = xm_p + (size_t)(b * 3) * XM_PLANE;
  const bf16* wb0    = kern_t + (size_t)(b * 27) * 4096 + lanelo * 64 + quad * 8;

  auto dma = [&](int p, int buf) {
    int m = p / 3, ky = p % 3;
    const bf16* src = plane0 + (size_t)m * XM_PLANE
                    + (size_t)(y + 7 + d * (ky - 1)) * XM_ROW;
    bf16* dst = sb + buf * BR_BUF;
    int base = wave * 576;               // 2304 chunks / 4 waves, 9 full instrs
#pragma unroll
    for (int r = 0; r < 9; ++r) {
      int u0 = base + r * 64;
      __builtin_amdgcn_global_load_lds((gas1)(src + (size_t)(u0 + lane) * 8),
                                       (las3)(dst + (size_t)u0 * 8), 16, 0, 0);
    }
  };

  f32x4 acc[4][4] = {};
  dma(0, 0);
  __syncthreads();

#pragma unroll
  for (int p = 0; p < 9; ++p) {
    int cur = p & 1;
    // areg(p): vector loads issued FIRST (kx-ordered; kx=1,2 latency hides under kx=0)
    int m = p / 3, ky = p % 3;
    const bf16* ap = wb0 + (size_t)(m * 9 + ky * 3) * 4096;
    bf16x8 areg[3][2][4];
#pragma unroll
    for (int kx = 0; kx < 3; ++kx)
#pragma unroll
      for (int kci = 0; kci < 2; ++kci)
#pragma unroll
        for (int mt = 0; mt < 4; ++mt)
          areg[kx][kci][mt] = *(const bf16x8*)(ap + kx * 4096 + mt * 1024 + kci * 32);
    // DMA(p+1): flies across the whole compute below
    if (p < 8) dma(p + 1, cur ^ 1);
    // compute on buf[cur]: [rr][cc][px][c8], aligned, 4-way b128 floor
    const bf16* bufb = sb + cur * BR_BUF + wr * 9088;
#pragma unroll
    for (int kx = 0; kx < 3; ++kx) {
      int p0 = 7 + d * (kx - 1) + wc * 64 + lanelo;
#pragma unroll
      for (int kci = 0; kci < 2; ++kci) {
        const bf16* bp = bufb + (kci * 4 + quad) * 1136 + p0 * 8;
        bf16x8 bv[4];
#pragma unroll
        for (int nt = 0; nt < 4; ++nt) bv[nt] = *(const bf16x8*)(bp + nt * 128);
#pragma unroll
        for (int mt = 0; mt < 4; ++mt)
#pragma unroll
          for (int nt = 0; nt < 4; ++nt)
            acc[mt][nt] = __builtin_amdgcn_mfma_f32_16x16x32_bf16(areg[kx][kci][mt], bv[nt], acc[mt][nt], 0, 0, 0);
      }
    }
    __syncthreads();   // drains DMA(p+1); guards buf[cur] reuse by DMA(p+2)
  }

  // epilogue: cat chunk-major [row y+wr+1][di][cc][px+1][c8]
  bf16* cp = cat_p + (size_t)b * CAT_PLANE + (size_t)(y + wr + 1) * CAT_ROW + di * CAT_DI;
#pragma unroll
  for (int mt = 0; mt < 4; ++mt) {
#pragma unroll
    for (int nt = 0; nt < 4; ++nt) {
      int px = wc * 64 + nt * 16 + lanelo;
      bf16x4 v;
#pragma unroll
      for (int r = 0; r < 4; ++r) v[r] = (bf16)acc[mt][nt][r];
      *(bf16x4*)(cp + (mt * 2 + (quad >> 1)) * 1040 + (px + 1) * 8 + (quad & 1) * 4) = v;
    }
  }
}

// ------- final conv + bias + BN + ReLU: same DMA-dbuf structure --------------
// block = 256 thr (wr x wc), tile = 64o x 128px x 2 rows. 12 phases (ky, dd).
__global__ __launch_bounds__(256, 2) void k_final(const bf16* __restrict__ cat_p,
                                                  const bf16* __restrict__ w2_t,
                                                  const float* __restrict__ cb,
                                                  const float* __restrict__ gamma,
                                                  const float* __restrict__ beta,
                                                  const float* __restrict__ mean,
                                                  const float* __restrict__ var,
                                                  float* __restrict__ out) {
  __shared__ bf16 sb[2 * FN_BUF];   // 73,728 B
  int bid = blockIdx.x;              // 0..255
  int xcd = bid & 7;
  int b   = xcd >> 1;
  int y   = (((bid >> 3) << 1) | (xcd & 1)) * 2;   // 0,2,..,126
  int t    = threadIdx.x;
  int lane = t & 63;
  int wave = t >> 6;
  int wr   = wave >> 1;
  int wc   = wave & 1;
  int lanelo = lane & 15;
  int quad = lane >> 4;

  const bf16* cbase = cat_p + (size_t)b * CAT_PLANE;
  const bf16* wbase = w2_t + lanelo * 256 + quad * 8;

  auto dma = [&](int p, int buf) {
    int ky = p >> 2, dd = p & 3;
    bf16* dst = sb + buf * FN_BUF;
#pragma unroll
    for (int rr = 0; rr < 2; ++rr) {
      const bf16* src = cbase + (size_t)(y + ky + rr) * CAT_ROW + (size_t)dd * CAT_DI;
      int base = wave * 288;             // 1152 chunks / 4 waves
#pragma unroll
      for (int r = 0; r < 4; ++r) {
        int u0 = base + r * 64;
        __builtin_amdgcn_global_load_lds((gas1)(src + (size_t)(u0 + lane) * 8),
                                         (las3)(dst + rr * FN_REG + (size_t)u0 * 8), 16, 0, 0);
      }
      int u0 = base + 256;
      if (lane < 32)
        __builtin_amdgcn_global_load_lds((gas1)(src + (size_t)(u0 + lane) * 8),
                                         (las3)(dst + rr * FN_REG + (size_t)u0 * 8), 16, 0, 0);
    }
  };

  f32x4 acc[4][4] = {};
  dma(0, 0);
  __syncthreads();

#pragma unroll
  for (int p = 0; p < 12; ++p) {
    int cur = p & 1;
    int ky = p >> 2, dd = p & 3;
    bf16x8 areg[3][2][4];
#pragma unroll
    for (int kx = 0; kx < 3; ++kx)
#pragma unroll
      for (int kci = 0; kci < 2; ++kci)
#pragma unroll
        for (int mt = 0; mt < 4; ++mt)
          areg[kx][kci][mt] = *(const bf16x8*)(wbase + (size_t)((ky * 3 + kx) * 64 + mt * 16) * 256
                                               + dd * 64 + kci * 32);
    if (p < 11) dma(p + 1, cur ^ 1);
    const bf16* bufb = sb + cur * FN_BUF + wr * FN_REG;
#pragma unroll
    for (int kx = 0; kx < 3; ++kx) {
      int p0 = wc * 64 + lanelo + kx;
#pragma unroll
      for (int kci = 0; kci < 2; ++kci) {
        const bf16* bp = bufb + (kci * 4 + quad) * 1040 + p0 * 8;
        bf16x8 bv[4];
#pragma unroll
        for (int nt = 0; nt < 4; ++nt) bv[nt] = *(const bf16x8*)(bp + nt * 128);
#pragma unroll
        for (int mt = 0; mt < 4; ++mt)
#pragma unroll
          for (int nt = 0; nt < 4; ++nt)
            acc[mt][nt] = __builtin_amdgcn_mfma_f32_16x16x32_bf16(areg[kx][kci][mt], bv[nt], acc[mt][nt], 0, 0, 0);
      }
    }
    __syncthreads();
  }

#pragma unroll
  for (int mt = 0; mt < 4; ++mt) {
#pragma unroll
    for (int nt = 0; nt < 4; ++nt) {
      int px = wc * 64 + nt * 16 + lanelo;
#pragma unroll
      for (int r = 0; r < 4; ++r) {
        int oc = mt * 16 + quad * 4 + r;
        float inv = gamma[oc] * rsqrtf(var[oc] + 1e-5f);
        float v = (acc[mt][nt][r] + cb[oc]) * inv + beta[oc] - mean[oc] * inv;
        out[((size_t)(b * 64 + oc)) * HW + (y + wr) * 128 + px] = fmaxf(v, 0.0f);
      }
    }
  }
}

extern "C" void kernel_launch(void* const* d_in, const int* in_sizes, int n_in,
                              void* d_out, int out_size, void* d_ws, size_t ws_size,
                              hipStream_t stream) {
  const float* x     = (const float*)d_in[0];
  const float* kern  = (const float*)d_in[1];
  const float* mw    = (const float*)d_in[2];
  const float* mb    = (const float*)d_in[3];
  const float* w2    = (const float*)d_in[4];
  const float* cb    = (const float*)d_in[5];
  const float* gamma = (const float*)d_in[6];
  const float* beta  = (const float*)d_in[7];
  const float* mean  = (const float*)d_in[8];
  const float* var   = (const float*)d_in[9];

  float* out   = (float*)d_out;
  float* masks = out + OUT_ELEMS;

  char* ws = (char*)d_ws;
  bf16* xm_p   = (bf16*)(ws);              // 30,971,904 B
  bf16* cat_p  = (bf16*)(ws + 30971904);   // 34,611,200 B (ends 65,583,104)
  bf16* kern_t = (bf16*)(ws + 65583104);   // 884,736 B (also absorbs DMA slack overreads)
  bf16* w2_t   = (bf16*)(ws + 66467840);   // 294,912 B -> total 66,762,752 B
  float* part  = (float*)(ws + 30971904);  // aliases cat_p; consumed before cat writes

  k_wt<<<2304, 256, 0, stream>>>(kern, w2, kern_t, w2_t);
  k_mask1<<<dim3(128, 4, 8), 128, 0, stream>>>(x, mw, part);
  k_mask2<<<dim3(128, 4), 128, 0, stream>>>(part, mb, masks);
  k_xmt<<<dim3(142, 3, 4), 256, 0, stream>>>(x, masks, xm_p);
  k_cat_halo<<<258, 256, 0, stream>>>(cat_p);
  k_branch<<<1024, 256, 0, stream>>>(xm_p, kern_t, cat_p);
  k_final<<<256, 256, 0, stream>>>(cat_p, w2_t, cb, gamma, beta, mean, var, out);
}